// Round 5
// baseline (1403.780 us; speedup 1.0000x reference)
//
#include <hip/hip_runtime.h>

#define N_NODES 200000
#define DIM 64
#define BSHIFT 8                       // 256 rows per dest bucket
#define BROWS 256
#define NB 782                         // ceil(200000 / 256)
#define NB_PAD 1024
#define CHUNK 4096                     // edges per bucket_scatter block
#define NS 8                           // source stripes (25000 nodes, 3.2 MB bf16 each)
#define NBINS 2048                     // 8 stripes x 256 rows per bucket_sort block
#define RS2_PITCH 257                  // per-(stripe,bucket) starts + sentinel

__device__ __forceinline__ float bf2f(unsigned short u) {
    return __uint_as_float(((unsigned int)u) << 16);
}
__device__ __forceinline__ unsigned short f2bf(float f) {
    unsigned int u = __float_as_uint(f);
    u += 0x7FFFu + ((u >> 16) & 1u);   // round-to-nearest-even
    return (unsigned short)(u >> 16);
}
__device__ __forceinline__ int stripe_of(int c) { return (int)((unsigned)c / 25000u); }

// ---- Pass A: dest-bucket histogram (LDS-staged) ----
__global__ __launch_bounds__(256) void bucket_hist(const int* __restrict__ rows, int E,
                                                   int* __restrict__ bcnt) {
    __shared__ int h[NB_PAD];
    for (int i = threadIdx.x; i < NB_PAD; i += 256) h[i] = 0;
    __syncthreads();
    int stride = gridDim.x * blockDim.x;
    for (int e = blockIdx.x * blockDim.x + threadIdx.x; e < E; e += stride)
        atomicAdd(&h[rows[e] >> BSHIFT], 1);
    __syncthreads();
    for (int i = threadIdx.x; i < NB; i += 256)
        if (h[i]) atomicAdd(&bcnt[i], h[i]);
}

// ---- Pass B: wave-parallel exclusive scan of 782 bucket counts ----
__global__ __launch_bounds__(1024) void bucket_scan(const int* __restrict__ bcnt,
                                                    int* __restrict__ bbase,
                                                    int* __restrict__ bcur) {
    __shared__ int wsum[16];
    int t = threadIdx.x;
    int v = (t < NB) ? bcnt[t] : 0;
    int incl = v;
    for (int off = 1; off < 64; off <<= 1) {
        int u = __shfl_up(incl, off);
        if ((t & 63) >= off) incl += u;
    }
    if ((t & 63) == 63) wsum[t >> 6] = incl;
    __syncthreads();
    if (t < 16) {
        int w = wsum[t];
        for (int off = 1; off < 16; off <<= 1) {
            int u = __shfl_up(w, off);
            if (t >= off) w += u;
        }
        wsum[t] = w;                    // inclusive wave sums
    }
    __syncthreads();
    int wb = (t >= 64) ? wsum[(t >> 6) - 1] : 0;
    int excl = wb + incl - v;
    if (t < NB) { bbase[t] = excl; bcur[t] = excl; }
    if (t == NB - 1) bbase[NB] = excl + v;
}

// ---- Pass C: chunked scatter into dest-bucket-grouped tmp (round-1 proven form) ----
__global__ __launch_bounds__(512) void bucket_scatter(const int* __restrict__ rows,
                                                      const int* __restrict__ cols,
                                                      const float* __restrict__ vals, int E,
                                                      int* __restrict__ bcur,
                                                      int2* __restrict__ tmp) {
    __shared__ int h[NB_PAD];          // counts, later reused as fix (g - excl)
    __shared__ int cur2[NB_PAD];       // block-local exclusive, then atomic cursor
    __shared__ int wtot[8];
    __shared__ int2 stage[CHUNK];
    __shared__ unsigned short sbkt[CHUNK];
    const int base = blockIdx.x * CHUNK;
    const int count = min(CHUNK, E - base);
    const int t = threadIdx.x;

    for (int i = t; i < NB_PAD; i += 512) h[i] = 0;
    __syncthreads();

    int myr[8], myc[8];
    float myv[8];
#pragma unroll
    for (int k = 0; k < 8; ++k) {
        int i = t + k * 512;
        if (i < count) {
            myr[k] = rows[base + i];
            myc[k] = cols[base + i];
            myv[k] = vals[base + i];
            atomicAdd(&h[myr[k] >> BSHIFT], 1);
        }
    }
    __syncthreads();

    // scan 1024 bins: 2 bins per thread, wave scan + cross-wave totals
    int h0 = h[2 * t], h1 = h[2 * t + 1];
    int s = h0 + h1;
    int incl = s;
    for (int off = 1; off < 64; off <<= 1) {
        int u = __shfl_up(incl, off);
        if ((t & 63) >= off) incl += u;
    }
    if ((t & 63) == 63) wtot[t >> 6] = incl;
    __syncthreads();
    int wb = 0;
    for (int w = 0; w < (t >> 6); ++w) wb += wtot[w];
    int excl = wb + incl - s;
    cur2[2 * t] = excl;
    cur2[2 * t + 1] = excl + h0;
    __syncthreads();

    // reserve global ranges; h becomes fix = g - excl
    for (int i = t; i < NB; i += 512) {
        int hi = h[i];
        int g = hi ? atomicAdd(&bcur[i], hi) : 0;
        h[i] = g - cur2[i];
    }
    __syncthreads();

    // stage in bucket-grouped order
#pragma unroll
    for (int k = 0; k < 8; ++k) {
        int i = t + k * 512;
        if (i < count) {
            int r = myr[k];
            int b = r >> BSHIFT;
            int slot = atomicAdd(&cur2[b], 1);
            stage[slot] = make_int2(((r & (BROWS - 1)) << 18) | myc[k], __float_as_int(myv[k]));
            sbkt[slot] = (unsigned short)b;
        }
    }
    __syncthreads();
    for (int s2 = t; s2 < count; s2 += 512)
        tmp[s2 + h[sbkt[s2]]] = stage[s2];
}

// ---- Pass D: per-bucket counting sort, STRIPE-MAJOR key, per-(stripe,row) CSR ----
// bin = (stripe << 8) | row_in_bucket: within a bucket, edges come out grouped by
// source stripe, then dest row. rs2[(s*NB+bk)*257 + rl] = segment start; entry 256
// is the sentinel (end of last row's stripe-s segment).
__global__ __launch_bounds__(512) void bucket_sort(const int2* __restrict__ tmp,
                                                   const int* __restrict__ bbase,
                                                   int2* __restrict__ sorted,
                                                   int* __restrict__ rs2) {
    __shared__ int h[NBINS];           // counts -> bases -> rank cursors
    __shared__ int wtot[8];
    const int bk = blockIdx.x;
    const int s0 = bbase[bk], s1 = bbase[bk + 1];
    const int t = threadIdx.x;
#pragma unroll
    for (int k = 0; k < NBINS / 512; ++k) h[t + k * 512] = 0;
    __syncthreads();
    for (int e = s0 + t; e < s1; e += 512) {
        int key = tmp[e].x;
        int bin = (stripe_of(key & 0x3FFFF) << 8) | (key >> 18);
        atomicAdd(&h[bin], 1);
    }
    __syncthreads();
    // scan 2048 bins: 4 per thread
    int b[4], ssum = 0;
#pragma unroll
    for (int k = 0; k < 4; ++k) { b[k] = h[4 * t + k]; ssum += b[k]; }
    int incl = ssum;
    for (int off = 1; off < 64; off <<= 1) {
        int u = __shfl_up(incl, off);
        if ((t & 63) >= off) incl += u;
    }
    if ((t & 63) == 63) wtot[t >> 6] = incl;
    __syncthreads();
    int wb = 0;
    for (int w = 0; w < (t >> 6); ++w) wb += wtot[w];
    int run = wb + incl - ssum;
#pragma unroll
    for (int k = 0; k < 4; ++k) { h[4 * t + k] = run; run += b[k]; }
    __syncthreads();
    // emit rs2 (starts + sentinel per stripe) while h still holds bases
    for (int i = t; i < NS * RS2_PITCH; i += 512) {
        int s = i / RS2_PITCH;
        int rl = i - s * RS2_PITCH;
        int val;
        if (rl < 256) val = s0 + h[(s << 8) + rl];
        else          val = (s < NS - 1) ? s0 + h[(s + 1) << 8] : s1;
        rs2[((size_t)s * NB + bk) * RS2_PITCH + rl] = val;
    }
    __syncthreads();
    for (int e = s0 + t; e < s1; e += 512) {
        int2 kv = tmp[e];
        int c = kv.x & 0x3FFFF;
        int bin = (stripe_of(c) << 8) | (kv.x >> 18);
        int rank = atomicAdd(&h[bin], 1);
        sorted[s0 + rank] = make_int2(c, kv.y);
    }
}

// ---- fp32 -> bf16 convert (embeds -> xb0) ----
__global__ __launch_bounds__(256) void convert_kernel(const float* __restrict__ src,
                                                      unsigned short* __restrict__ dst, int n4) {
    int i = blockIdx.x * blockDim.x + threadIdx.x;
    if (i >= n4) return;
    float4 v = *(const float4*)(src + i * 4);
    ushort4 o;
    o.x = f2bf(v.x); o.y = f2bf(v.y); o.z = f2bf(v.z); o.w = f2bf(v.w);
    *(ushort4*)(dst + i * 4) = o;
}

// ---- SpMM: phase-swept, all-co-resident, register-accumulated ----
// One block per 256-row dest bucket; 4 blocks/CU -> all 782 blocks co-resident.
// All blocks sweep stripe 0..7 in lockstep (work per (bucket,stripe) = 1024 +- 3%),
// so the machine-wide gather footprint during phase s is one 3.2 MB stripe (< 4 MB
// L2/XCD). Thread owns 8 consecutive rows x 8 feats; acc in 64 VGPRs.
#define BF_LO(u) __uint_as_float((u) << 16)
#define BF_HI(u) __uint_as_float((u) & 0xFFFF0000u)
#define FMA8A(A, G, V)                          \
    do {                                        \
        A[0] = fmaf((V), BF_LO((G).x), A[0]);   \
        A[1] = fmaf((V), BF_HI((G).x), A[1]);   \
        A[2] = fmaf((V), BF_LO((G).y), A[2]);   \
        A[3] = fmaf((V), BF_HI((G).y), A[3]);   \
        A[4] = fmaf((V), BF_LO((G).z), A[4]);   \
        A[5] = fmaf((V), BF_HI((G).z), A[5]);   \
        A[6] = fmaf((V), BF_LO((G).w), A[6]);   \
        A[7] = fmaf((V), BF_HI((G).w), A[7]);   \
    } while (0)

__global__ __launch_bounds__(256, 4) void spmm_kernel(const int2* __restrict__ sorted,
                                                      const int* __restrict__ rs2,
                                                      const unsigned short* __restrict__ xb,
                                                      unsigned short* __restrict__ y) {
    __shared__ int rsl[NS * RS2_PITCH];
    const int bk = blockIdx.x;
    const int t = threadIdx.x;
    for (int i = t; i < NS * RS2_PITCH; i += 256) {
        int s = i / RS2_PITCH;
        rsl[i] = rs2[((size_t)s * NB + bk) * RS2_PITCH + (i - s * RS2_PITCH)];
    }
    __syncthreads();

    const int j = (t & 7) << 3;
    const int rl0 = t >> 3;            // 0..31; thread rows = rl0*8 + k, k=0..7
    const unsigned short* xbj = xb + j;
    float acc_[8][8];
#pragma unroll
    for (int k = 0; k < 8; ++k)
#pragma unroll
        for (int i = 0; i < 8; ++i) acc_[k][i] = 0.f;

#pragma unroll
    for (int s = 0; s < NS; ++s) {
#pragma unroll
        for (int k = 0; k < 8; ++k) {
            int rl = (rl0 << 3) + k;
            int e = rsl[s * RS2_PITCH + rl];
            int eend = rsl[s * RS2_PITCH + rl + 1];
            for (; e + 2 <= eend; e += 2) {
                long long r0 = __builtin_nontemporal_load((const long long*)(sorted + e));
                long long r1 = __builtin_nontemporal_load((const long long*)(sorted + e + 1));
                int c0 = (int)(unsigned int)r0;
                int c1 = (int)(unsigned int)r1;
                float v0 = __int_as_float((int)((unsigned long long)r0 >> 32));
                float v1 = __int_as_float((int)((unsigned long long)r1 >> 32));
                uint4 g0 = *(const uint4*)(xbj + (c0 << 6));
                uint4 g1 = *(const uint4*)(xbj + (c1 << 6));
                FMA8A(acc_[k], g0, v0);
                FMA8A(acc_[k], g1, v1);
            }
            if (e < eend) {
                long long r0 = __builtin_nontemporal_load((const long long*)(sorted + e));
                int c0 = (int)(unsigned int)r0;
                float v0 = __int_as_float((int)((unsigned long long)r0 >> 32));
                uint4 g0 = *(const uint4*)(xbj + (c0 << 6));
                FMA8A(acc_[k], g0, v0);
            }
        }
    }

#pragma unroll
    for (int k = 0; k < 8; ++k) {
        int r = (bk << 8) + (rl0 << 3) + k;
        if (r < N_NODES) {
            uint4 yo;
            yo.x = (unsigned)f2bf(acc_[k][0]) | ((unsigned)f2bf(acc_[k][1]) << 16);
            yo.y = (unsigned)f2bf(acc_[k][2]) | ((unsigned)f2bf(acc_[k][3]) << 16);
            yo.z = (unsigned)f2bf(acc_[k][4]) | ((unsigned)f2bf(acc_[k][5]) << 16);
            yo.w = (unsigned)f2bf(acc_[k][6]) | ((unsigned)f2bf(acc_[k][7]) << 16);
            *(uint4*)(y + (r << 6) + j) = yo;
        }
    }
}

// ---- final merge: acc = 0.2 * (embeds + y1 + y2 + y3 + y4), pure streaming ----
__global__ __launch_bounds__(256) void merge_kernel(const float* __restrict__ emb,
                                                    const unsigned short* __restrict__ y1,
                                                    const unsigned short* __restrict__ y2,
                                                    const unsigned short* __restrict__ y3,
                                                    const unsigned short* __restrict__ y4,
                                                    float* __restrict__ acc, int n8) {
    int i = blockIdx.x * blockDim.x + threadIdx.x;
    if (i >= n8) return;
    int o = i * 8;
    uint4 a = *(const uint4*)(y1 + o);
    uint4 b = *(const uint4*)(y2 + o);
    uint4 c = *(const uint4*)(y3 + o);
    uint4 d = *(const uint4*)(y4 + o);
    float4 x0 = *(const float4*)(emb + o);
    float4 x1 = *(const float4*)(emb + o + 4);
    const float sc = 0.2f;
    float4 o0, o1;
    o0.x = (x0.x + BF_LO(a.x) + BF_LO(b.x) + BF_LO(c.x) + BF_LO(d.x)) * sc;
    o0.y = (x0.y + BF_HI(a.x) + BF_HI(b.x) + BF_HI(c.x) + BF_HI(d.x)) * sc;
    o0.z = (x0.z + BF_LO(a.y) + BF_LO(b.y) + BF_LO(c.y) + BF_LO(d.y)) * sc;
    o0.w = (x0.w + BF_HI(a.y) + BF_HI(b.y) + BF_HI(c.y) + BF_HI(d.y)) * sc;
    o1.x = (x1.x + BF_LO(a.z) + BF_LO(b.z) + BF_LO(c.z) + BF_LO(d.z)) * sc;
    o1.y = (x1.y + BF_HI(a.z) + BF_HI(b.z) + BF_HI(c.z) + BF_HI(d.z)) * sc;
    o1.z = (x1.z + BF_LO(a.w) + BF_LO(b.w) + BF_LO(c.w) + BF_LO(d.w)) * sc;
    o1.w = (x1.w + BF_HI(a.w) + BF_HI(b.w) + BF_HI(c.w) + BF_HI(d.w)) * sc;
    *(float4*)(acc + o) = o0;
    *(float4*)(acc + o + 4) = o1;
}

extern "C" void kernel_launch(void* const* d_in, const int* in_sizes, int n_in,
                              void* d_out, int out_size, void* d_ws, size_t ws_size,
                              hipStream_t stream) {
    const float* embeds = (const float*)d_in[0];
    const int*   rows   = (const int*)d_in[1];
    const int*   cols   = (const int*)d_in[2];
    const float* vals   = (const float*)d_in[3];
    float* acc = (float*)d_out;
    const int E = in_sizes[1];

    char* ws = (char*)d_ws;
    size_t off = 0;
    auto alloc = [&](size_t bytes) -> char* {
        char* p = ws + off;
        off = (off + bytes + 255) & ~(size_t)255;
        return p;
    };
    int*   bcnt   = (int*)alloc((size_t)NB * 4);
    int*   bbase  = (int*)alloc((size_t)(NB + 1) * 4);
    int*   bcur   = (int*)alloc((size_t)NB * 4);
    int*   rs2    = (int*)alloc((size_t)NS * NB * RS2_PITCH * 4);            // 6.4 MB
    int2*  sorted = (int2*)alloc((size_t)E * 8);                             // 51.2 MB
    unsigned short* xb0 = (unsigned short*)alloc((size_t)N_NODES * DIM * 2); // 25.6 MB
    unsigned short* xb1 = (unsigned short*)alloc((size_t)N_NODES * DIM * 2); // 25.6 MB
    unsigned short* xb2 = (unsigned short*)alloc((size_t)N_NODES * DIM * 2); // 25.6 MB
    int2*  tmp    = (int2*)alloc((size_t)E * 8);                             // 51.2 MB
    // xb3/xb4 alias tmp (dead after bucket_sort); tmp = 51.2 MB = exactly 2x25.6
    unsigned short* xb3 = (unsigned short*)tmp;
    unsigned short* xb4 = xb3 + (size_t)N_NODES * DIM;

    hipMemsetAsync(bcnt, 0, (size_t)NB * 4, stream);

    bucket_hist<<<1024, 256, 0, stream>>>(rows, E, bcnt);
    bucket_scan<<<1, 1024, 0, stream>>>(bcnt, bbase, bcur);
    bucket_scatter<<<(E + CHUNK - 1) / CHUNK, 512, 0, stream>>>(rows, cols, vals, E, bcur, tmp);
    bucket_sort<<<NB, 512, 0, stream>>>(tmp, bbase, sorted, rs2);

    int n4 = N_NODES * DIM / 4;
    convert_kernel<<<(n4 + 255) / 256, 256, 0, stream>>>(embeds, xb0, n4);

    spmm_kernel<<<NB, 256, 0, stream>>>(sorted, rs2, xb0, xb1);
    spmm_kernel<<<NB, 256, 0, stream>>>(sorted, rs2, xb1, xb2);
    spmm_kernel<<<NB, 256, 0, stream>>>(sorted, rs2, xb2, xb3);
    spmm_kernel<<<NB, 256, 0, stream>>>(sorted, rs2, xb3, xb4);

    int n8 = N_NODES * DIM / 8;
    merge_kernel<<<(n8 + 255) / 256, 256, 0, stream>>>(embeds, xb1, xb2, xb3, xb4, acc, n8);
}

// Round 6
// 1273.444 us; speedup vs baseline: 1.1023x; 1.1023x over previous
//
#include <hip/hip_runtime.h>

#define N_NODES 200000
#define DIM 64
#define BSHIFT 8                       // 256 rows per dest bucket
#define BROWS 256
#define NB 782                         // ceil(200000 / 256)
#define NB_PAD 1024
#define CHUNK 4096                     // edges per bucket_scatter block
#define NS 8                           // source stripes (25000 nodes, 3.2 MB bf16 each)
#define NBINS 2048                     // 8 stripes x 256 rows per bucket_sort block
#define RS2_PITCH 257                  // per-(stripe,bucket) starts + sentinel
#define ECAP 1536                      // staged edges per (bucket,stripe); overflow -> global

__device__ __forceinline__ float bf2f(unsigned short u) {
    return __uint_as_float(((unsigned int)u) << 16);
}
__device__ __forceinline__ unsigned short f2bf(float f) {
    unsigned int u = __float_as_uint(f);
    u += 0x7FFFu + ((u >> 16) & 1u);   // round-to-nearest-even
    return (unsigned short)(u >> 16);
}
__device__ __forceinline__ int stripe_of(int c) { return (int)((unsigned)c / 25000u); }

// ---- Pass A: dest-bucket histogram (LDS-staged) ----
__global__ __launch_bounds__(256) void bucket_hist(const int* __restrict__ rows, int E,
                                                   int* __restrict__ bcnt) {
    __shared__ int h[NB_PAD];
    for (int i = threadIdx.x; i < NB_PAD; i += 256) h[i] = 0;
    __syncthreads();
    int stride = gridDim.x * blockDim.x;
    for (int e = blockIdx.x * blockDim.x + threadIdx.x; e < E; e += stride)
        atomicAdd(&h[rows[e] >> BSHIFT], 1);
    __syncthreads();
    for (int i = threadIdx.x; i < NB; i += 256)
        if (h[i]) atomicAdd(&bcnt[i], h[i]);
}

// ---- Pass B: wave-parallel exclusive scan of 782 bucket counts ----
__global__ __launch_bounds__(1024) void bucket_scan(const int* __restrict__ bcnt,
                                                    int* __restrict__ bbase,
                                                    int* __restrict__ bcur) {
    __shared__ int wsum[16];
    int t = threadIdx.x;
    int v = (t < NB) ? bcnt[t] : 0;
    int incl = v;
    for (int off = 1; off < 64; off <<= 1) {
        int u = __shfl_up(incl, off);
        if ((t & 63) >= off) incl += u;
    }
    if ((t & 63) == 63) wsum[t >> 6] = incl;
    __syncthreads();
    if (t < 16) {
        int w = wsum[t];
        for (int off = 1; off < 16; off <<= 1) {
            int u = __shfl_up(w, off);
            if (t >= off) w += u;
        }
        wsum[t] = w;                    // inclusive wave sums
    }
    __syncthreads();
    int wb = (t >= 64) ? wsum[(t >> 6) - 1] : 0;
    int excl = wb + incl - v;
    if (t < NB) { bbase[t] = excl; bcur[t] = excl; }
    if (t == NB - 1) bbase[NB] = excl + v;
}

// ---- Pass C: chunked scatter into dest-bucket-grouped tmp (round-1 proven form) ----
__global__ __launch_bounds__(512) void bucket_scatter(const int* __restrict__ rows,
                                                      const int* __restrict__ cols,
                                                      const float* __restrict__ vals, int E,
                                                      int* __restrict__ bcur,
                                                      int2* __restrict__ tmp) {
    __shared__ int h[NB_PAD];          // counts, later reused as fix (g - excl)
    __shared__ int cur2[NB_PAD];       // block-local exclusive, then atomic cursor
    __shared__ int wtot[8];
    __shared__ int2 stage[CHUNK];
    __shared__ unsigned short sbkt[CHUNK];
    const int base = blockIdx.x * CHUNK;
    const int count = min(CHUNK, E - base);
    const int t = threadIdx.x;

    for (int i = t; i < NB_PAD; i += 512) h[i] = 0;
    __syncthreads();

    int myr[8], myc[8];
    float myv[8];
#pragma unroll
    for (int k = 0; k < 8; ++k) {
        int i = t + k * 512;
        if (i < count) {
            myr[k] = rows[base + i];
            myc[k] = cols[base + i];
            myv[k] = vals[base + i];
            atomicAdd(&h[myr[k] >> BSHIFT], 1);
        }
    }
    __syncthreads();

    // scan 1024 bins: 2 bins per thread, wave scan + cross-wave totals
    int h0 = h[2 * t], h1 = h[2 * t + 1];
    int s = h0 + h1;
    int incl = s;
    for (int off = 1; off < 64; off <<= 1) {
        int u = __shfl_up(incl, off);
        if ((t & 63) >= off) incl += u;
    }
    if ((t & 63) == 63) wtot[t >> 6] = incl;
    __syncthreads();
    int wb = 0;
    for (int w = 0; w < (t >> 6); ++w) wb += wtot[w];
    int excl = wb + incl - s;
    cur2[2 * t] = excl;
    cur2[2 * t + 1] = excl + h0;
    __syncthreads();

    // reserve global ranges; h becomes fix = g - excl
    for (int i = t; i < NB; i += 512) {
        int hi = h[i];
        int g = hi ? atomicAdd(&bcur[i], hi) : 0;
        h[i] = g - cur2[i];
    }
    __syncthreads();

    // stage in bucket-grouped order
#pragma unroll
    for (int k = 0; k < 8; ++k) {
        int i = t + k * 512;
        if (i < count) {
            int r = myr[k];
            int b = r >> BSHIFT;
            int slot = atomicAdd(&cur2[b], 1);
            stage[slot] = make_int2(((r & (BROWS - 1)) << 18) | myc[k], __float_as_int(myv[k]));
            sbkt[slot] = (unsigned short)b;
        }
    }
    __syncthreads();
    for (int s2 = t; s2 < count; s2 += 512)
        tmp[s2 + h[sbkt[s2]]] = stage[s2];
}

// ---- Pass D: per-bucket counting sort, STRIPE-MAJOR key, per-(stripe,row) CSR ----
__global__ __launch_bounds__(512) void bucket_sort(const int2* __restrict__ tmp,
                                                   const int* __restrict__ bbase,
                                                   int2* __restrict__ sorted,
                                                   int* __restrict__ rs2) {
    __shared__ int h[NBINS];           // counts -> bases -> rank cursors
    __shared__ int wtot[8];
    const int bk = blockIdx.x;
    const int s0 = bbase[bk], s1 = bbase[bk + 1];
    const int t = threadIdx.x;
#pragma unroll
    for (int k = 0; k < NBINS / 512; ++k) h[t + k * 512] = 0;
    __syncthreads();
    for (int e = s0 + t; e < s1; e += 512) {
        int key = tmp[e].x;
        int bin = (stripe_of(key & 0x3FFFF) << 8) | (key >> 18);
        atomicAdd(&h[bin], 1);
    }
    __syncthreads();
    // scan 2048 bins: 4 per thread
    int b[4], ssum = 0;
#pragma unroll
    for (int k = 0; k < 4; ++k) { b[k] = h[4 * t + k]; ssum += b[k]; }
    int incl = ssum;
    for (int off = 1; off < 64; off <<= 1) {
        int u = __shfl_up(incl, off);
        if ((t & 63) >= off) incl += u;
    }
    if ((t & 63) == 63) wtot[t >> 6] = incl;
    __syncthreads();
    int wb = 0;
    for (int w = 0; w < (t >> 6); ++w) wb += wtot[w];
    int run = wb + incl - ssum;
#pragma unroll
    for (int k = 0; k < 4; ++k) { h[4 * t + k] = run; run += b[k]; }
    __syncthreads();
    // emit rs2 (starts + sentinel per stripe) while h still holds bases
    for (int i = t; i < NS * RS2_PITCH; i += 512) {
        int s = i / RS2_PITCH;
        int rl = i - s * RS2_PITCH;
        int val;
        if (rl < 256) val = s0 + h[(s << 8) + rl];
        else          val = (s < NS - 1) ? s0 + h[(s + 1) << 8] : s1;
        rs2[((size_t)s * NB + bk) * RS2_PITCH + rl] = val;
    }
    __syncthreads();
    for (int e = s0 + t; e < s1; e += 512) {
        int2 kv = tmp[e];
        int c = kv.x & 0x3FFFF;
        int bin = (stripe_of(c) << 8) | (kv.x >> 18);
        int rank = atomicAdd(&h[bin], 1);
        sorted[s0 + rank] = make_int2(c, kv.y);
    }
}

// ---- fp32 -> bf16 convert (embeds -> xb0) ----
__global__ __launch_bounds__(256) void convert_kernel(const float* __restrict__ src,
                                                      unsigned short* __restrict__ dst, int n4) {
    int i = blockIdx.x * blockDim.x + threadIdx.x;
    if (i >= n4) return;
    float4 v = *(const float4*)(src + i * 4);
    ushort4 o;
    o.x = f2bf(v.x); o.y = f2bf(v.y); o.z = f2bf(v.z); o.w = f2bf(v.w);
    *(ushort4*)(dst + i * 4) = o;
}

// ---- SpMM: phase-swept + LDS-staged edges + 4-chain ILP ----
// 782 blocks x 512 threads (3 blocks/CU, ~24 waves/CU). All blocks sweep stripes
// 0..7 near-lockstep -> machine-wide gather footprint = one 3.2 MB stripe (L2).
// Edges for (bucket, stripe) are contiguous (stripe-major sort); staged into LDS
// double-buffered: nt-loads for stripe s+1 issued BEFORE compute of stripe s
// (T14 issue-early/write-late), so edge latency hides under gathers. Thread owns
// 4 rows x 8 feats (32 VGPR acc); 4 independent row-chains give 4 gathers in flight.
#define BF_LO(u) __uint_as_float((u) << 16)
#define BF_HI(u) __uint_as_float((u) & 0xFFFF0000u)
#define FMA8A(A, G, V)                          \
    do {                                        \
        A[0] = fmaf((V), BF_LO((G).x), A[0]);   \
        A[1] = fmaf((V), BF_HI((G).x), A[1]);   \
        A[2] = fmaf((V), BF_LO((G).y), A[2]);   \
        A[3] = fmaf((V), BF_HI((G).y), A[3]);   \
        A[4] = fmaf((V), BF_LO((G).z), A[4]);   \
        A[5] = fmaf((V), BF_HI((G).z), A[5]);   \
        A[6] = fmaf((V), BF_HI((G).w) * 0.f + BF_LO((G).w), A[6]);   \
        A[7] = fmaf((V), BF_HI((G).w), A[7]);   \
    } while (0)
// note: A[6] line is just BF_LO((G).w); written defensively to avoid macro typo
#undef FMA8A
#define FMA8A(A, G, V)                          \
    do {                                        \
        A[0] = fmaf((V), BF_LO((G).x), A[0]);   \
        A[1] = fmaf((V), BF_HI((G).x), A[1]);   \
        A[2] = fmaf((V), BF_LO((G).y), A[2]);   \
        A[3] = fmaf((V), BF_HI((G).y), A[3]);   \
        A[4] = fmaf((V), BF_LO((G).z), A[4]);   \
        A[5] = fmaf((V), BF_HI((G).z), A[5]);   \
        A[6] = fmaf((V), BF_LO((G).w), A[6]);   \
        A[7] = fmaf((V), BF_HI((G).w), A[7]);   \
    } while (0)

__global__ __launch_bounds__(512) void spmm_kernel(const int2* __restrict__ sorted,
                                                   const int* __restrict__ rs2,
                                                   const unsigned short* __restrict__ xb,
                                                   unsigned short* __restrict__ y) {
    __shared__ int rsl[NS * RS2_PITCH];
    __shared__ long long ebuf[2][ECAP];
    const int bk = blockIdx.x;
    const int t = threadIdx.x;
    for (int i = t; i < NS * RS2_PITCH; i += 512) {
        int s = i / RS2_PITCH;
        rsl[i] = rs2[((size_t)s * NB + bk) * RS2_PITCH + (i - s * RS2_PITCH)];
    }
    __syncthreads();

    const int j = (t & 7) << 3;        // feat offset (8 lanes x 8 feats = 64)
    const int rg = t >> 3;             // 0..63; thread rows = rg*4 + k
    const unsigned short* xbj = xb + j;
    const long long* sortedll = (const long long*)sorted;

    float acc[4][8];
#pragma unroll
    for (int k = 0; k < 4; ++k)
#pragma unroll
        for (int i = 0; i < 8; ++i) acc[k][i] = 0.f;

    // prologue: stage stripe 0 into ebuf[0]
    int curA = rsl[0];
    int curcnt = min(rsl[256] - curA, ECAP);
    {
        long long q0 = 0, q1 = 0, q2 = 0;
        if (t < curcnt)        q0 = __builtin_nontemporal_load(sortedll + curA + t);
        if (t + 512 < curcnt)  q1 = __builtin_nontemporal_load(sortedll + curA + t + 512);
        if (t + 1024 < curcnt) q2 = __builtin_nontemporal_load(sortedll + curA + t + 1024);
        if (t < curcnt)        ebuf[0][t] = q0;
        if (t + 512 < curcnt)  ebuf[0][t + 512] = q1;
        if (t + 1024 < curcnt) ebuf[0][t + 1024] = q2;
    }
    __syncthreads();

#pragma unroll 1
    for (int s = 0; s < NS; ++s) {
        // issue next stripe's edge loads (land during compute below)
        int nA = 0, ncnt = 0;
        long long p0 = 0, p1 = 0, p2 = 0;
        if (s + 1 < NS) {
            nA = rsl[(s + 1) * RS2_PITCH];
            ncnt = min(rsl[(s + 1) * RS2_PITCH + 256] - nA, ECAP);
            if (t < ncnt)        p0 = __builtin_nontemporal_load(sortedll + nA + t);
            if (t + 512 < ncnt)  p1 = __builtin_nontemporal_load(sortedll + nA + t + 512);
            if (t + 1024 < ncnt) p2 = __builtin_nontemporal_load(sortedll + nA + t + 1024);
        }

        // compute stripe s from LDS (4 independent row-chains)
        const long long* buf = ebuf[s & 1];
        int ek[4], en[4];
        {
            const int rb = s * RS2_PITCH + (rg << 2);
            int b0 = rsl[rb], b1 = rsl[rb + 1], b2 = rsl[rb + 2];
            int b3 = rsl[rb + 3], b4 = rsl[rb + 4];
            ek[0] = b0; en[0] = b1;
            ek[1] = b1; en[1] = b2;
            ek[2] = b2; en[2] = b3;
            ek[3] = b3; en[3] = b4;
        }
        while (true) {
            bool a0 = ek[0] < en[0], a1 = ek[1] < en[1];
            bool a2 = ek[2] < en[2], a3 = ek[3] < en[3];
            if (!(a0 | a1 | a2 | a3)) break;
#pragma unroll
            for (int k = 0; k < 4; ++k) {
                if (ek[k] < en[k]) {
                    int idx = ek[k] - curA;
                    long long q;
                    if (idx < curcnt) q = buf[idx];
                    else              q = sortedll[ek[k]];
                    int c = (int)(unsigned int)q;
                    float v = __int_as_float((int)((unsigned long long)q >> 32));
                    uint4 g = *(const uint4*)(xbj + (c << 6));
                    FMA8A(acc[k], g, v);
                    ek[k]++;
                }
            }
        }

        // write staged edges for stripe s+1, then barrier
        if (s + 1 < NS) {
            long long* nb = ebuf[(s + 1) & 1];
            if (t < ncnt)        nb[t] = p0;
            if (t + 512 < ncnt)  nb[t + 512] = p1;
            if (t + 1024 < ncnt) nb[t + 1024] = p2;
        }
        __syncthreads();
        curA = nA; curcnt = ncnt;
    }

#pragma unroll
    for (int k = 0; k < 4; ++k) {
        int r = (bk << 8) + (rg << 2) + k;
        if (r < N_NODES) {
            uint4 yo;
            yo.x = (unsigned)f2bf(acc[k][0]) | ((unsigned)f2bf(acc[k][1]) << 16);
            yo.y = (unsigned)f2bf(acc[k][2]) | ((unsigned)f2bf(acc[k][3]) << 16);
            yo.z = (unsigned)f2bf(acc[k][4]) | ((unsigned)f2bf(acc[k][5]) << 16);
            yo.w = (unsigned)f2bf(acc[k][6]) | ((unsigned)f2bf(acc[k][7]) << 16);
            *(uint4*)(y + (r << 6) + j) = yo;
        }
    }
}

// ---- final merge: acc = 0.2 * (embeds + y1 + y2 + y3 + y4), pure streaming ----
__global__ __launch_bounds__(256) void merge_kernel(const float* __restrict__ emb,
                                                    const unsigned short* __restrict__ y1,
                                                    const unsigned short* __restrict__ y2,
                                                    const unsigned short* __restrict__ y3,
                                                    const unsigned short* __restrict__ y4,
                                                    float* __restrict__ acc, int n8) {
    int i = blockIdx.x * blockDim.x + threadIdx.x;
    if (i >= n8) return;
    int o = i * 8;
    uint4 a = *(const uint4*)(y1 + o);
    uint4 b = *(const uint4*)(y2 + o);
    uint4 c = *(const uint4*)(y3 + o);
    uint4 d = *(const uint4*)(y4 + o);
    float4 x0 = *(const float4*)(emb + o);
    float4 x1 = *(const float4*)(emb + o + 4);
    const float sc = 0.2f;
    float4 o0, o1;
    o0.x = (x0.x + BF_LO(a.x) + BF_LO(b.x) + BF_LO(c.x) + BF_LO(d.x)) * sc;
    o0.y = (x0.y + BF_HI(a.x) + BF_HI(b.x) + BF_HI(c.x) + BF_HI(d.x)) * sc;
    o0.z = (x0.z + BF_LO(a.y) + BF_LO(b.y) + BF_LO(c.y) + BF_LO(d.y)) * sc;
    o0.w = (x0.w + BF_HI(a.y) + BF_HI(b.y) + BF_HI(c.y) + BF_HI(d.y)) * sc;
    o1.x = (x1.x + BF_LO(a.z) + BF_LO(b.z) + BF_LO(c.z) + BF_LO(d.z)) * sc;
    o1.y = (x1.y + BF_HI(a.z) + BF_HI(b.z) + BF_HI(c.z) + BF_HI(d.z)) * sc;
    o1.z = (x1.z + BF_LO(a.w) + BF_LO(b.w) + BF_LO(c.w) + BF_LO(d.w)) * sc;
    o1.w = (x1.w + BF_HI(a.w) + BF_HI(b.w) + BF_HI(c.w) + BF_HI(d.w)) * sc;
    *(float4*)(acc + o) = o0;
    *(float4*)(acc + o + 4) = o1;
}

extern "C" void kernel_launch(void* const* d_in, const int* in_sizes, int n_in,
                              void* d_out, int out_size, void* d_ws, size_t ws_size,
                              hipStream_t stream) {
    const float* embeds = (const float*)d_in[0];
    const int*   rows   = (const int*)d_in[1];
    const int*   cols   = (const int*)d_in[2];
    const float* vals   = (const float*)d_in[3];
    float* acc = (float*)d_out;
    const int E = in_sizes[1];

    char* ws = (char*)d_ws;
    size_t off = 0;
    auto alloc = [&](size_t bytes) -> char* {
        char* p = ws + off;
        off = (off + bytes + 255) & ~(size_t)255;
        return p;
    };
    int*   bcnt   = (int*)alloc((size_t)NB * 4);
    int*   bbase  = (int*)alloc((size_t)(NB + 1) * 4);
    int*   bcur   = (int*)alloc((size_t)NB * 4);
    int*   rs2    = (int*)alloc((size_t)NS * NB * RS2_PITCH * 4);            // 6.4 MB
    int2*  sorted = (int2*)alloc((size_t)E * 8);                             // 51.2 MB
    unsigned short* xb0 = (unsigned short*)alloc((size_t)N_NODES * DIM * 2); // 25.6 MB
    unsigned short* xb1 = (unsigned short*)alloc((size_t)N_NODES * DIM * 2); // 25.6 MB
    unsigned short* xb2 = (unsigned short*)alloc((size_t)N_NODES * DIM * 2); // 25.6 MB
    int2*  tmp    = (int2*)alloc((size_t)E * 8);                             // 51.2 MB
    // xb3/xb4 alias tmp (dead after bucket_sort); tmp = 51.2 MB = exactly 2x25.6
    unsigned short* xb3 = (unsigned short*)tmp;
    unsigned short* xb4 = xb3 + (size_t)N_NODES * DIM;

    hipMemsetAsync(bcnt, 0, (size_t)NB * 4, stream);

    bucket_hist<<<1024, 256, 0, stream>>>(rows, E, bcnt);
    bucket_scan<<<1, 1024, 0, stream>>>(bcnt, bbase, bcur);
    bucket_scatter<<<(E + CHUNK - 1) / CHUNK, 512, 0, stream>>>(rows, cols, vals, E, bcur, tmp);
    bucket_sort<<<NB, 512, 0, stream>>>(tmp, bbase, sorted, rs2);

    int n4 = N_NODES * DIM / 4;
    convert_kernel<<<(n4 + 255) / 256, 256, 0, stream>>>(embeds, xb0, n4);

    spmm_kernel<<<NB, 512, 0, stream>>>(sorted, rs2, xb0, xb1);
    spmm_kernel<<<NB, 512, 0, stream>>>(sorted, rs2, xb1, xb2);
    spmm_kernel<<<NB, 512, 0, stream>>>(sorted, rs2, xb2, xb3);
    spmm_kernel<<<NB, 512, 0, stream>>>(sorted, rs2, xb3, xb4);

    int n8 = N_NODES * DIM / 8;
    merge_kernel<<<(n8 + 255) / 256, 256, 0, stream>>>(embeds, xb1, xb2, xb3, xb4, acc, n8);
}